// Round 1
// baseline (196.122 us; speedup 1.0000x reference)
//
#include <hip/hip_runtime.h>

// SmoothL1 (beta=0.5) masked sum reduction, N = 16M fixed.
// sl1 = ad < 0.5 ? d*d : ad - 0.25  (0.5*d*d/0.5 == d*d exactly: pow-2)
// mask: ad >= 1.0f/len; out[0] = sum(mask ? sl1 : 0)
//
// R5 -> R6: cache-policy experiment. nt loads (R5, 51us) hit MALL at ~50%
// (FETCH_SIZE 100MB of 201MB) but never ALLOCATE on miss -> residency frozen.
// Inputs (192 MiB) fit in the 256 MiB memory-side Infinity Cache. sc1 (device
// scope, nt=0) streams past the per-XCD L2 (avoiding the 73us L2-thrash of
// plain cached loads) while MALL, being memory-side, fills with normal
// temporal policy on every miss -> steady-state ~100% MALL residency.
// Inline asm loads are invisible to compiler waitcnt insertion, so the
// software pipeline uses hand-counted s_waitcnt vmcnt(3) + sched_barrier(0)
// (volatile asm order is preserved; vmcnt retires in issue order).
// FP summation order is bit-identical to R5 (absmax was 0.0 - keep it).

#define N_TOTAL 16777216
#define NVEC    (N_TOTAL / 4)       // 4194304 vec4 groups
#define BLOCK   256
#define GRID    2048                // 8 blocks/CU, 32 waves/CU
#define ITERS   (NVEC / (BLOCK * GRID))   // 8 iterations/thread, exact cover

typedef float f32x4 __attribute__((ext_vector_type(4)));
typedef int   i32x4 __attribute__((ext_vector_type(4)));

__device__ __forceinline__ f32x4 load_sc1_f4(const f32x4* p) {
    f32x4 r;
    asm volatile("global_load_dwordx4 %0, %1, off sc1"
                 : "=&v"(r) : "v"(p));
    return r;
}

__device__ __forceinline__ i32x4 load_sc1_i4(const i32x4* p) {
    i32x4 r;
    asm volatile("global_load_dwordx4 %0, %1, off sc1"
                 : "=&v"(r) : "v"(p));
    return r;
}

__device__ __forceinline__ float sl1_term(float o, float l, int len) {
    float d  = o - l;
    float ad = fabsf(d);
    float v  = (ad < 0.5f) ? (d * d) : (ad - 0.25f);
    float boundary = 1.0f / (float)len;   // IEEE divide; matches jnp 1/len
    return (ad >= boundary) ? v : 0.0f;
}

__global__ __launch_bounds__(BLOCK) void RegressionLoss_45440753992375_kernel(
        const float* __restrict__ outs,
        const float* __restrict__ labels,
        const int*   __restrict__ lens,
        float* __restrict__ out) {
    const f32x4* o4 = (const f32x4*)outs;
    const f32x4* l4 = (const f32x4*)labels;
    const i32x4* n4 = (const i32x4*)lens;

    // Block-contiguous: block b owns [b*BLOCK*ITERS, ...), thread strides BLOCK.
    int i = blockIdx.x * (BLOCK * ITERS) + threadIdx.x;

    // Pipeline stage 0: 3 loads outstanding.
    f32x4 o_c = load_sc1_f4(o4 + i);
    f32x4 l_c = load_sc1_f4(l4 + i);
    i32x4 n_c = load_sc1_i4(n4 + i);

    float acc = 0.0f;
    #pragma unroll
    for (int it = 0; it < ITERS - 1; ++it) {
        i += BLOCK;
        // Issue next-iteration loads: 6 outstanding, oldest 3 are current's.
        f32x4 o_n = load_sc1_f4(o4 + i);
        f32x4 l_n = load_sc1_f4(l4 + i);
        i32x4 n_n = load_sc1_i4(n4 + i);

        // Wait for the current iteration's 3 loads (issue-order retirement),
        // keep next 3 in flight. sched_barrier pins consumption below the wait.
        asm volatile("s_waitcnt vmcnt(3)" ::: "memory");
        __builtin_amdgcn_sched_barrier(0);

        acc += sl1_term(o_c.x, l_c.x, n_c.x);
        acc += sl1_term(o_c.y, l_c.y, n_c.y);
        acc += sl1_term(o_c.z, l_c.z, n_c.z);
        acc += sl1_term(o_c.w, l_c.w, n_c.w);

        o_c = o_n; l_c = l_n; n_c = n_n;
    }
    asm volatile("s_waitcnt vmcnt(0)" ::: "memory");
    __builtin_amdgcn_sched_barrier(0);
    acc += sl1_term(o_c.x, l_c.x, n_c.x);
    acc += sl1_term(o_c.y, l_c.y, n_c.y);
    acc += sl1_term(o_c.z, l_c.z, n_c.z);
    acc += sl1_term(o_c.w, l_c.w, n_c.w);

    // wave-64 shuffle reduction
    #pragma unroll
    for (int off = 32; off > 0; off >>= 1)
        acc += __shfl_down(acc, off, 64);

    __shared__ float smem[BLOCK / 64];
    const int lane = threadIdx.x & 63;
    const int wid  = threadIdx.x >> 6;
    if (lane == 0) smem[wid] = acc;
    __syncthreads();
    if (threadIdx.x == 0) {
        float bsum = smem[0] + smem[1] + smem[2] + smem[3];
        atomicAdd(out, bsum);   // device-scope by default on CDNA
    }
}

extern "C" void kernel_launch(void* const* d_in, const int* in_sizes, int n_in,
                              void* d_out, int out_size, void* d_ws, size_t ws_size,
                              hipStream_t stream) {
    const float* outs   = (const float*)d_in[0];
    const float* labels = (const float*)d_in[1];
    const int*   lens   = (const int*)d_in[2];
    float* out = (float*)d_out;

    // d_out is poisoned 0xAA before every timed launch — zero it on-stream.
    hipMemsetAsync(out, 0, sizeof(float), stream);

    RegressionLoss_45440753992375_kernel<<<GRID, BLOCK, 0, stream>>>(outs, labels, lens, out);
}

// Round 2
// 194.601 us; speedup vs baseline: 1.0078x; 1.0078x over previous
//
#include <hip/hip_runtime.h>

// SmoothL1 (beta=0.5) masked sum reduction, N = 16M fixed.
// sl1 = ad < 0.5 ? d*d : ad - 0.25  (0.5*d*d/0.5 == d*d exactly: pow-2)
// mask: ad >= 1.0f/len; out[0] = sum(mask ? sl1 : 0)
//
// Cache-policy ladder so far (192 MiB stream, fits 256 MiB MALL):
//   plain (000):  73 us  -- L2 allocate/evict machinery throttles (~2.75 TB/s)
//   nt   (nt=1):  51 us  -- L2 bypassed, but MALL no-allocate: residency frozen
//                          at ~50% (FETCH 98 MB/launch forever), 3.93 TB/s eff.
//   sc1  (R6):    74 us  -- sc1 alone = agent scope, L2 STILL allocates ->
//                          reproduced the plain plateau. FETCH unchanged.
// R7: sc0+sc1 (system scope), nt=0. Expect: L2 bypass (like nt) but MALL
// allocates on miss -> steady-state ~100% MALL residency across launches.
// Signature A (win): FETCH -> <20 MB, dur -> 30-40 us.
// Signature B (bypass-all): FETCH -> ~197 MB, dur ~32-40 us if HBM streams.
// FP summation order bit-identical to R5/R6 (absmax 0.0 - keep it).

#define N_TOTAL 16777216
#define NVEC    (N_TOTAL / 4)       // 4194304 vec4 groups
#define BLOCK   256
#define GRID    2048                // 8 blocks/CU, 32 waves/CU
#define ITERS   (NVEC / (BLOCK * GRID))   // 8 iterations/thread, exact cover

typedef float f32x4 __attribute__((ext_vector_type(4)));
typedef int   i32x4 __attribute__((ext_vector_type(4)));

__device__ __forceinline__ f32x4 load_sys_f4(const f32x4* p) {
    f32x4 r;
    asm volatile("global_load_dwordx4 %0, %1, off sc0 sc1"
                 : "=&v"(r) : "v"(p));
    return r;
}

__device__ __forceinline__ i32x4 load_sys_i4(const i32x4* p) {
    i32x4 r;
    asm volatile("global_load_dwordx4 %0, %1, off sc0 sc1"
                 : "=&v"(r) : "v"(p));
    return r;
}

__device__ __forceinline__ float sl1_term(float o, float l, int len) {
    float d  = o - l;
    float ad = fabsf(d);
    float v  = (ad < 0.5f) ? (d * d) : (ad - 0.25f);
    float boundary = 1.0f / (float)len;   // IEEE divide; matches jnp 1/len
    return (ad >= boundary) ? v : 0.0f;
}

__global__ __launch_bounds__(BLOCK) void RegressionLoss_45440753992375_kernel(
        const float* __restrict__ outs,
        const float* __restrict__ labels,
        const int*   __restrict__ lens,
        float* __restrict__ out) {
    const f32x4* o4 = (const f32x4*)outs;
    const f32x4* l4 = (const f32x4*)labels;
    const i32x4* n4 = (const i32x4*)lens;

    // Block-contiguous: block b owns [b*BLOCK*ITERS, ...), thread strides BLOCK.
    int i = blockIdx.x * (BLOCK * ITERS) + threadIdx.x;

    // Pipeline stage 0: 3 loads outstanding.
    f32x4 o_c = load_sys_f4(o4 + i);
    f32x4 l_c = load_sys_f4(l4 + i);
    i32x4 n_c = load_sys_i4(n4 + i);

    float acc = 0.0f;
    #pragma unroll
    for (int it = 0; it < ITERS - 1; ++it) {
        i += BLOCK;
        // Issue next-iteration loads: 6 outstanding, oldest 3 are current's.
        f32x4 o_n = load_sys_f4(o4 + i);
        f32x4 l_n = load_sys_f4(l4 + i);
        i32x4 n_n = load_sys_i4(n4 + i);

        // Wait for the current iteration's 3 loads (issue-order retirement),
        // keep next 3 in flight. sched_barrier pins consumption below the wait.
        asm volatile("s_waitcnt vmcnt(3)" ::: "memory");
        __builtin_amdgcn_sched_barrier(0);

        acc += sl1_term(o_c.x, l_c.x, n_c.x);
        acc += sl1_term(o_c.y, l_c.y, n_c.y);
        acc += sl1_term(o_c.z, l_c.z, n_c.z);
        acc += sl1_term(o_c.w, l_c.w, n_c.w);

        o_c = o_n; l_c = l_n; n_c = n_n;
    }
    asm volatile("s_waitcnt vmcnt(0)" ::: "memory");
    __builtin_amdgcn_sched_barrier(0);
    acc += sl1_term(o_c.x, l_c.x, n_c.x);
    acc += sl1_term(o_c.y, l_c.y, n_c.y);
    acc += sl1_term(o_c.z, l_c.z, n_c.z);
    acc += sl1_term(o_c.w, l_c.w, n_c.w);

    // wave-64 shuffle reduction
    #pragma unroll
    for (int off = 32; off > 0; off >>= 1)
        acc += __shfl_down(acc, off, 64);

    __shared__ float smem[BLOCK / 64];
    const int lane = threadIdx.x & 63;
    const int wid  = threadIdx.x >> 6;
    if (lane == 0) smem[wid] = acc;
    __syncthreads();
    if (threadIdx.x == 0) {
        float bsum = smem[0] + smem[1] + smem[2] + smem[3];
        atomicAdd(out, bsum);   // device-scope by default on CDNA
    }
}

extern "C" void kernel_launch(void* const* d_in, const int* in_sizes, int n_in,
                              void* d_out, int out_size, void* d_ws, size_t ws_size,
                              hipStream_t stream) {
    const float* outs   = (const float*)d_in[0];
    const float* labels = (const float*)d_in[1];
    const int*   lens   = (const int*)d_in[2];
    float* out = (float*)d_out;

    // d_out is poisoned 0xAA before every timed launch — zero it on-stream.
    hipMemsetAsync(out, 0, sizeof(float), stream);

    RegressionLoss_45440753992375_kernel<<<GRID, BLOCK, 0, stream>>>(outs, labels, lens, out);
}

// Round 3
// 186.171 us; speedup vs baseline: 1.0534x; 1.0453x over previous
//
#include <hip/hip_runtime.h>

// SmoothL1 (beta=0.5) masked sum reduction, N = 16M fixed.
// sl1 = ad < 0.5 ? d*d : ad - 0.25  (0.5*d*d/0.5 == d*d exactly: pow-2)
// mask: ad >= 1.0f/len; out[0] = sum(mask ? sl1 : 0)
//
// Cache-policy ladder (192 MiB stream/launch):
//   plain (000):   73 us -- L2 allocate/evict machinery throttles
//   sc1 / sc0sc1:  74-75 us -- scope bits still L2-allocate; same plateau
//   nt   (nt=1):   51 us -- L2 bypass; 3.93 TB/s effective
// FETCH_SIZE identical (98343 KB = exactly half) across ALL policies ->
// counter artifact (subset of XCD TCC channels), not 50% MALL hits. Model:
// full 192 MiB streams from memory every launch; nt's win is purely skipping
// L2 allocate. No residency to chase -> remaining lever is MLP.
//
// R8: revert to builtin nt loads (known-good 51 us codegen) + deepen the
// software pipeline to depth-2: 9 dwordx4 outstanding per thread (3 full
// iterations in flight), register-rotated, fully unrolled.
// launch_bounds(256,8) pins VGPR <= 64 so 8 waves/SIMD is kept.
// FP summation order bit-identical to R5 (absmax 0.0 - keep it).

#define N_TOTAL 16777216
#define NVEC    (N_TOTAL / 4)       // 4194304 vec4 groups
#define BLOCK   256
#define GRID    2048                // 8 blocks/CU, 32 waves/CU
#define ITERS   (NVEC / (BLOCK * GRID))   // 8 iterations/thread, exact cover

typedef float f32x4 __attribute__((ext_vector_type(4)));
typedef int   i32x4 __attribute__((ext_vector_type(4)));

__device__ __forceinline__ float sl1_term(float o, float l, int len) {
    float d  = o - l;
    float ad = fabsf(d);
    float v  = (ad < 0.5f) ? (d * d) : (ad - 0.25f);
    float boundary = 1.0f / (float)len;   // IEEE divide; matches jnp 1/len
    return (ad >= boundary) ? v : 0.0f;
}

__device__ __forceinline__ float consume4(f32x4 o, f32x4 l, i32x4 n) {
    float s = 0.0f;
    s += sl1_term(o.x, l.x, n.x);
    s += sl1_term(o.y, l.y, n.y);
    s += sl1_term(o.z, l.z, n.z);
    s += sl1_term(o.w, l.w, n.w);
    return s;
}

__global__ __launch_bounds__(BLOCK, 8) void RegressionLoss_45440753992375_kernel(
        const float* __restrict__ outs,
        const float* __restrict__ labels,
        const int*   __restrict__ lens,
        float* __restrict__ out) {
    const f32x4* o4 = (const f32x4*)outs;
    const f32x4* l4 = (const f32x4*)labels;
    const i32x4* n4 = (const i32x4*)lens;

    // Block-contiguous: block b owns [b*BLOCK*ITERS, ...), thread strides BLOCK.
    const int base = blockIdx.x * (BLOCK * ITERS) + threadIdx.x;

    // Pipeline prologue: iterations 0 and 1 in flight (6 loads).
    f32x4 oA = __builtin_nontemporal_load(o4 + base);
    f32x4 lA = __builtin_nontemporal_load(l4 + base);
    i32x4 nA = __builtin_nontemporal_load(n4 + base);

    f32x4 oB = __builtin_nontemporal_load(o4 + base + BLOCK);
    f32x4 lB = __builtin_nontemporal_load(l4 + base + BLOCK);
    i32x4 nB = __builtin_nontemporal_load(n4 + base + BLOCK);

    float acc = 0.0f;
    #pragma unroll
    for (int it = 0; it < ITERS - 2; ++it) {
        // Issue iteration it+2 (9 outstanding) before consuming iteration it.
        const int idx = base + (it + 2) * BLOCK;
        f32x4 oC = __builtin_nontemporal_load(o4 + idx);
        f32x4 lC = __builtin_nontemporal_load(l4 + idx);
        i32x4 nC = __builtin_nontemporal_load(n4 + idx);

        acc += consume4(oA, lA, nA);

        // Rotate stages (register renaming; loop fully unrolled).
        oA = oB; lA = lB; nA = nB;
        oB = oC; lB = lC; nB = nC;
    }
    acc += consume4(oA, lA, nA);   // iteration ITERS-2
    acc += consume4(oB, lB, nB);   // iteration ITERS-1

    // wave-64 shuffle reduction
    #pragma unroll
    for (int off = 32; off > 0; off >>= 1)
        acc += __shfl_down(acc, off, 64);

    __shared__ float smem[BLOCK / 64];
    const int lane = threadIdx.x & 63;
    const int wid  = threadIdx.x >> 6;
    if (lane == 0) smem[wid] = acc;
    __syncthreads();
    if (threadIdx.x == 0) {
        float bsum = smem[0] + smem[1] + smem[2] + smem[3];
        atomicAdd(out, bsum);   // device-scope by default on CDNA
    }
}

extern "C" void kernel_launch(void* const* d_in, const int* in_sizes, int n_in,
                              void* d_out, int out_size, void* d_ws, size_t ws_size,
                              hipStream_t stream) {
    const float* outs   = (const float*)d_in[0];
    const float* labels = (const float*)d_in[1];
    const int*   lens   = (const int*)d_in[2];
    float* out = (float*)d_out;

    // d_out is poisoned 0xAA before every timed launch — zero it on-stream.
    hipMemsetAsync(out, 0, sizeof(float), stream);

    RegressionLoss_45440753992375_kernel<<<GRID, BLOCK, 0, stream>>>(outs, labels, lens, out);
}